// Round 6
// baseline (178.073 us; speedup 1.0000x reference)
//
#include <hip/hip_runtime.h>
#include <math.h>

#define BATCH 32
#define MROWS 120
#define JDIM  64
#define DIM   512
#define NROW  (BATCH * MROWS)   // 3840
#define MPAD  128
#define DQ    (DIM / 4)         // 128 float4-chunks per row

#define NCHUNK 15               // n-chunks per batch
#define NC_LEN 8                // n-rows per chunk
#define K2BLK  (BATCH * NCHUNK) // 480

#define LOGIT_SCALE 14.285714285714283f

typedef float f4 __attribute__((ext_vector_type(4)));

// ---------------------------------------------------------------------------
// K1: skel_f[b,m,:] = normalize( sum_j skeleton[b,m,j,:] )   (1/64 cancels)
// one block per (b,m); 256 threads; linear float4 stream of the 128 KB slab.
// ---------------------------------------------------------------------------
__global__ __launch_bounds__(256) void k_skel_mean_norm(
    const float* __restrict__ skel_in, float* __restrict__ skel_f)
{
    const int row = blockIdx.x;          // b*120 + m
    const int t   = threadIdx.x;         // 0..255
    const int wid = t >> 6, lane = t & 63;

    const f4* __restrict__ src =
        (const f4*)(skel_in + (size_t)row * (JDIM * DIM));

    f4 acc = (f4){0.f, 0.f, 0.f, 0.f};
    #pragma unroll 8
    for (int it = 0; it < 32; ++it)
        acc += src[it * 256 + t];        // 256 lanes x 16B = 4 KB contiguous

    // combine even-j half (t<128) with odd-j half (t+128), same d4 slot
    __shared__ f4 part[128];
    if (t >= 128) part[t - 128] = acc;
    __syncthreads();

    float ss = 0.f;
    if (t < 128) {
        acc += part[t];
        ss = acc.x * acc.x + acc.y * acc.y + acc.z * acc.z + acc.w * acc.w;
    }

    #pragma unroll
    for (int o = 32; o > 0; o >>= 1) ss += __shfl_xor(ss, o, 64);
    __shared__ float wsum[4];
    if (lane == 0) wsum[wid] = ss;
    __syncthreads();
    const float inv = 1.0f / sqrtf(wsum[0] + wsum[1] + wsum[2] + wsum[3]);

    if (t < 128) {
        f4* __restrict__ dst = (f4*)(skel_f + (size_t)row * DIM);
        dst[t] = acc * inv;
    }
}

// ---------------------------------------------------------------------------
// Kt: textT4[b][dq][m] = float4(text[b][m][4dq..4dq+3])  via LDS tile.
// block = (b, 32-d tile); 512 blocks x 256 threads.
// phase 1: coalesced 128B row-segments -> LDS [32][121] (conflict-free)
// phase 2: coalesced float4 stores, lane = m (1 KB per wave-store)
// ---------------------------------------------------------------------------
__global__ __launch_bounds__(256) void k_text_transpose(
    const float* __restrict__ text, f4* __restrict__ textT4)
{
    const int b    = blockIdx.x >> 4;    // 0..31
    const int tile = blockIdx.x & 15;    // 0..15 (32 d's each)
    const int t    = threadIdx.x;        // 0..255

    __shared__ float lds[32 * 121];      // [dj][m], pad 121

    // phase 1: read text[b][m][tile*32 + 4c .. +3] for all m
    const int c  = t & 7;                // float4-chunk within the 32-d tile
    const int ml = t >> 3;               // 0..31
    #pragma unroll
    for (int p = 0; p < 4; ++p) {
        const int m = p * 32 + ml;       // 0..127
        f4 v = (f4){0.f, 0.f, 0.f, 0.f};
        if (m < MROWS)
            v = ((const f4*)text)[((size_t)(b * MROWS + m) * DIM >> 2)
                                  + tile * 8 + c];
        lds[(4 * c + 0) * 121 + m] = v.x;
        lds[(4 * c + 1) * 121 + m] = v.y;
        lds[(4 * c + 2) * 121 + m] = v.z;
        lds[(4 * c + 3) * 121 + m] = v.w;
    }
    __syncthreads();

    // phase 2: textT4[b][tile*8 + dq][m], lane = m -> fully coalesced
    const int m   = t & 127;
    const int dq0 = t >> 7;              // 0..1
    #pragma unroll
    for (int k = 0; k < 4; ++k) {
        const int dq = dq0 + 2 * k;      // 0..7
        f4 o;
        o.x = lds[(4 * dq + 0) * 121 + m];
        o.y = lds[(4 * dq + 1) * 121 + m];
        o.z = lds[(4 * dq + 2) * 121 + m];
        o.w = lds[(4 * dq + 3) * 121 + m];
        textT4[((size_t)b * DQ + tile * 8 + dq) * MPAD + m] = o;
    }
}

// ---------------------------------------------------------------------------
// K2: block = (b, nc); 128 threads; lane t = text row m.
// acc[k] = sum_d text[b][t][d] * skel_f[b][n0+k][d]
//   tv4 : coalesced 16B/lane loads from textT4 (L2-resident)
//   skel: wave-uniform float4 -> scalar s_load, zero cross-lane reduction
//   ||text||^2 accumulated in the same loop (no scale array)
// per-lane LSE partial over the 8 local n + diagonal capture.
// ---------------------------------------------------------------------------
__global__ __launch_bounds__(128) void k_logits(
    const f4* __restrict__ textT4, const float* __restrict__ skel_f,
    float* __restrict__ part_mx, float* __restrict__ part_se,
    float* __restrict__ diag)
{
    const int blk = blockIdx.x;          // b*NCHUNK + nc
    const int b   = blk / NCHUNK;
    const int nc  = blk - b * NCHUNK;
    const int n0  = nc * NC_LEN;
    const int t   = threadIdx.x;         // 0..127 (m; 120..127 inert)

    const f4* __restrict__ tT = textT4 + (size_t)b * DQ * MPAD + t;
    const f4* __restrict__ sk =
        (const f4*)(skel_f + ((size_t)b * MROWS + n0) * DIM);

    float acc[NC_LEN];
    #pragma unroll
    for (int k = 0; k < NC_LEN; ++k) acc[k] = 0.f;
    float ss = 0.f;

    #pragma unroll 4
    for (int dq = 0; dq < DQ; ++dq) {
        const f4 tv = tT[(size_t)dq * MPAD];
        ss += tv.x * tv.x + tv.y * tv.y + tv.z * tv.z + tv.w * tv.w;
        #pragma unroll
        for (int k = 0; k < NC_LEN; ++k) {
            const f4 s = sk[k * DQ + dq];      // wave-uniform -> s_load
            acc[k] = fmaf(tv.x, s.x,
                     fmaf(tv.y, s.y,
                     fmaf(tv.z, s.z,
                     fmaf(tv.w, s.w, acc[k]))));
        }
    }

    if (t < MROWS) {
        const float sc = LOGIT_SCALE / sqrtf(ss);

        float lg[NC_LEN];
        float mx = -INFINITY;
        #pragma unroll
        for (int k = 0; k < NC_LEN; ++k) {
            lg[k] = sc * acc[k];
            mx = fmaxf(mx, lg[k]);
        }
        float se = 0.f;
        #pragma unroll
        for (int k = 0; k < NC_LEN; ++k) se += expf(lg[k] - mx);

        part_mx[(size_t)blk * MPAD + t] = mx;
        part_se[(size_t)blk * MPAD + t] = se;

        if ((t >> 3) == nc)              // this chunk holds n == t
            diag[b * MPAD + t] = lg[t & 7];
    }
}

// ---------------------------------------------------------------------------
// K3: single block; combine 15 LSE partials per (b,m), sum diag-lse, finish.
// thread handles (b,m) = (p>>7, p&127) for p = t, t+1024, t+2048, t+3072.
// ---------------------------------------------------------------------------
__global__ __launch_bounds__(1024) void k_combine_final(
    const float* __restrict__ part_mx, const float* __restrict__ part_se,
    const float* __restrict__ diag, float* __restrict__ out)
{
    const int t = threadIdx.x;
    const int wid = t >> 6, lane = t & 63;

    float sum = 0.f;
    #pragma unroll
    for (int k = 0; k < 4; ++k) {
        const int p = t + k * 1024;      // 0..4095
        const int b = p >> 7, m = p & 127;
        if (m < MROWS) {
            float mx = -INFINITY;
            #pragma unroll
            for (int nc = 0; nc < NCHUNK; ++nc)
                mx = fmaxf(mx, part_mx[(size_t)(b * NCHUNK + nc) * MPAD + m]);
            float se = 0.f;
            #pragma unroll
            for (int nc = 0; nc < NCHUNK; ++nc) {
                const size_t i = (size_t)(b * NCHUNK + nc) * MPAD + m;
                se += part_se[i] * expf(part_mx[i] - mx);
            }
            sum += diag[b * MPAD + m] - (mx + logf(se));
        }
    }

    #pragma unroll
    for (int o = 32; o > 0; o >>= 1) sum += __shfl_xor(sum, o, 64);
    __shared__ float wsum[16];
    if (lane == 0) wsum[wid] = sum;
    __syncthreads();
    if (t == 0) {
        float s = 0.f;
        #pragma unroll
        for (int w = 0; w < 16; ++w) s += wsum[w];
        out[0] = -s * (1.0f / (float)NROW);
    }
}

extern "C" void kernel_launch(void* const* d_in, const int* in_sizes, int n_in,
                              void* d_out, int out_size, void* d_ws, size_t ws_size,
                              hipStream_t stream)
{
    const float* skel_in = (const float*)d_in[0];   // (32,120,64,512) f32
    const float* text    = (const float*)d_in[1];   // (32,120,512)    f32
    float* out = (float*)d_out;

    float* skel_f  = (float*)d_ws;                        // 3840*512 f32
    f4*    textT4  = (f4*)(skel_f + (size_t)NROW * DIM);  // 32*128*128 f4
    float* part_mx = (float*)(textT4 + (size_t)BATCH * DQ * MPAD);
    float* part_se = part_mx + (size_t)K2BLK * MPAD;
    float* diag    = part_se + (size_t)K2BLK * MPAD;

    k_skel_mean_norm<<<NROW,      256, 0, stream>>>(skel_in, skel_f);
    k_text_transpose<<<BATCH * 16, 256, 0, stream>>>(text, textT4);
    k_logits        <<<K2BLK,     128, 0, stream>>>(textT4, skel_f,
                                                    part_mx, part_se, diag);
    k_combine_final <<<1,        1024, 0, stream>>>(part_mx, part_se, diag, out);
}

// Round 7
// 137.707 us; speedup vs baseline: 1.2931x; 1.2931x over previous
//
#include <hip/hip_runtime.h>
#include <math.h>

#define BATCH 32
#define MROWS 120
#define JDIM  64
#define DIM   512
#define NROW  (BATCH * MROWS)   // 3840

#define LOGIT_SCALE 14.285714285714283f

typedef float  f4     __attribute__((ext_vector_type(4)));
typedef float  f32x4  __attribute__((ext_vector_type(4)));
typedef short  bf16x8 __attribute__((ext_vector_type(8)));
typedef unsigned short u16x4 __attribute__((ext_vector_type(4)));

static __device__ __forceinline__ unsigned short f2bf(float f) {
    // round-to-nearest-even fp32 -> bf16 (inputs are finite normals)
    unsigned int u = __float_as_uint(f);
    u += 0x7FFFu + ((u >> 16) & 1u);
    return (unsigned short)(u >> 16);
}

// ---------------------------------------------------------------------------
// K1: skel_bf[b,m,:] = bf16( sum_j skeleton[b,m,j,:] / ||sum_j ...|| )
// (mean/||mean|| == sum/||sum||). One block per (b,m); 256 threads;
// linear float4 stream of the 128 KB slab (R3's proven pattern).
// ---------------------------------------------------------------------------
__global__ __launch_bounds__(256) void k_skel_mean_norm(
    const float* __restrict__ skel_in, unsigned short* __restrict__ skel_bf)
{
    const int row = blockIdx.x;          // b*120 + m
    const int t   = threadIdx.x;         // 0..255
    const int wid = t >> 6, lane = t & 63;

    const f4* __restrict__ src =
        (const f4*)(skel_in + (size_t)row * (JDIM * DIM));

    f4 acc = (f4){0.f, 0.f, 0.f, 0.f};
    #pragma unroll 8
    for (int it = 0; it < 32; ++it)
        acc += src[it * 256 + t];        // 256 lanes x 16B = 4 KB contiguous

    __shared__ f4 part[128];
    if (t >= 128) part[t - 128] = acc;
    __syncthreads();

    float ss = 0.f;
    if (t < 128) {
        acc += part[t];
        ss = acc.x * acc.x + acc.y * acc.y + acc.z * acc.z + acc.w * acc.w;
    }

    #pragma unroll
    for (int o = 32; o > 0; o >>= 1) ss += __shfl_xor(ss, o, 64);
    __shared__ float wsum[4];
    if (lane == 0) wsum[wid] = ss;
    __syncthreads();
    const float inv = 1.0f / sqrtf(wsum[0] + wsum[1] + wsum[2] + wsum[3]);

    if (t < 128) {
        u16x4 o;
        o.x = f2bf(acc.x * inv);
        o.y = f2bf(acc.y * inv);
        o.z = f2bf(acc.z * inv);
        o.w = f2bf(acc.w * inv);
        *(u16x4*)(skel_bf + (size_t)row * DIM + 4 * t) = o;
    }
}

// ---------------------------------------------------------------------------
// Kt: text_bf[b,m,:] = bf16( LOGIT_SCALE * text[b,m,:] / ||text[b,m,:]|| )
// one block per (b,m); 128 threads.
// ---------------------------------------------------------------------------
__global__ __launch_bounds__(128) void k_text_prep(
    const float* __restrict__ text, unsigned short* __restrict__ text_bf)
{
    const int row = blockIdx.x;          // b*120 + m
    const int t   = threadIdx.x;         // 0..127
    const int wid = t >> 6, lane = t & 63;

    f4 v = ((const f4*)(text + (size_t)row * DIM))[t];
    float ss = v.x * v.x + v.y * v.y + v.z * v.z + v.w * v.w;
    #pragma unroll
    for (int o = 32; o > 0; o >>= 1) ss += __shfl_xor(ss, o, 64);

    __shared__ float red[2];
    if (lane == 0) red[wid] = ss;
    __syncthreads();
    const float sc = LOGIT_SCALE / sqrtf(red[0] + red[1]);

    u16x4 o;
    o.x = f2bf(v.x * sc);
    o.y = f2bf(v.y * sc);
    o.z = f2bf(v.z * sc);
    o.w = f2bf(v.w * sc);
    *(u16x4*)(text_bf + (size_t)row * DIM + 4 * t) = o;
}

// ---------------------------------------------------------------------------
// K2: per batch b: logits(120x120) = text_bf(120x512) . skel_bf(120x512)^T
// via mfma_f32_16x16x32_bf16, then in-register row-LSE + diagonal.
// block = b (32 blocks, 512 threads = 8 waves). Wave w: rows 16w..16w+15,
// all 128 cols (8 col-tiles). A-frag: lane reads text row (l&15), 8 contig
// k at k0+(l>>4)*8. B-frag: same pattern on skel row 16*tc+(l&15).
// C/D layout (HW-verified): col = lane&15, row = (lane>>4)*4 + reg.
// ---------------------------------------------------------------------------
__global__ __launch_bounds__(512) void k_logits_mfma(
    const unsigned short* __restrict__ text_bf,
    const unsigned short* __restrict__ skel_bf,
    float* __restrict__ bpart)
{
    const int b  = blockIdx.x;
    const int t  = threadIdx.x;
    const int w  = t >> 6;               // wave 0..7
    const int l  = t & 63;
    const int cl = l & 15;               // A-row / B-col within tile
    const int cg = l >> 4;               // k-subgroup; also C row-group

    const int arow = 16 * w + cl;
    const bool a_ok = (arow < MROWS);
    const unsigned short* __restrict__ ta =
        text_bf + ((size_t)b * MROWS + arow) * DIM;
    const unsigned short* __restrict__ sb =
        skel_bf + (size_t)b * MROWS * DIM;

    const bf16x8 zerov = (bf16x8){0,0,0,0,0,0,0,0};

    f32x4 acc[8];
    #pragma unroll
    for (int i = 0; i < 8; ++i) acc[i] = (f32x4){0.f, 0.f, 0.f, 0.f};

    for (int ks = 0; ks < 16; ++ks) {
        const int k0 = ks * 32 + cg * 8;
        const bf16x8 a = a_ok ? *(const bf16x8*)(ta + k0) : zerov;
        #pragma unroll
        for (int tc = 0; tc < 8; ++tc) {
            const int n = 16 * tc + cl;
            const bf16x8 bb = (n < MROWS)
                ? *(const bf16x8*)(sb + (size_t)n * DIM + k0) : zerov;
            acc[tc] = __builtin_amdgcn_mfma_f32_16x16x32_bf16(a, bb, acc[tc],
                                                              0, 0, 0);
        }
    }

    // per-row LSE + diagonal. Row (w, cg, r) = 16w + 4cg + r lives in the
    // 16 lanes of group cg, spread over 8 tiles (cols 16tc + cl).
    float csum = 0.f;
    #pragma unroll
    for (int r = 0; r < 4; ++r) {
        const int row = 16 * w + 4 * cg + r;

        float mx = -INFINITY;
        #pragma unroll
        for (int tc = 0; tc < 8; ++tc)
            if (16 * tc + cl < MROWS) mx = fmaxf(mx, acc[tc][r]);
        #pragma unroll
        for (int o = 1; o < 16; o <<= 1) mx = fmaxf(mx, __shfl_xor(mx, o, 16));

        float se = 0.f;
        #pragma unroll
        for (int tc = 0; tc < 8; ++tc)
            if (16 * tc + cl < MROWS) se += expf(acc[tc][r] - mx);
        #pragma unroll
        for (int o = 1; o < 16; o <<= 1) se += __shfl_xor(se, o, 16);

        // diagonal col == row -> tile tc = w, lane cl = 4cg + r
        if (row < MROWS && cl == 4 * cg + r)
            csum += acc[w][r] - (mx + logf(se));
    }

    #pragma unroll
    for (int o = 32; o > 0; o >>= 1) csum += __shfl_xor(csum, o, 64);
    __shared__ float wsums[8];
    if (l == 0) wsums[w] = csum;
    __syncthreads();
    if (t == 0) {
        float s = 0.f;
        #pragma unroll
        for (int i = 0; i < 8; ++i) s += wsums[i];
        bpart[b] = s;
    }
}

// ---------------------------------------------------------------------------
// K3: out = -sum(bpart) / NROW
// ---------------------------------------------------------------------------
__global__ __launch_bounds__(64) void k_final(
    const float* __restrict__ bpart, float* __restrict__ out)
{
    const int t = threadIdx.x;
    float s = (t < BATCH) ? bpart[t] : 0.f;
    #pragma unroll
    for (int o = 32; o > 0; o >>= 1) s += __shfl_xor(s, o, 64);
    if (t == 0) out[0] = -s * (1.0f / (float)NROW);
}

extern "C" void kernel_launch(void* const* d_in, const int* in_sizes, int n_in,
                              void* d_out, int out_size, void* d_ws, size_t ws_size,
                              hipStream_t stream)
{
    const float* skel_in = (const float*)d_in[0];   // (32,120,64,512) f32
    const float* text    = (const float*)d_in[1];   // (32,120,512)    f32
    float* out = (float*)d_out;

    unsigned short* skel_bf = (unsigned short*)d_ws;            // 3.93 MB
    unsigned short* text_bf = skel_bf + (size_t)NROW * DIM;     // 3.93 MB
    float*          bpart   = (float*)(text_bf + (size_t)NROW * DIM); // 32

    k_skel_mean_norm<<<NROW, 256, 0, stream>>>(skel_in, skel_bf);
    k_text_prep     <<<NROW, 128, 0, stream>>>(text, text_bf);
    k_logits_mfma   <<<BATCH, 512, 0, stream>>>(text_bf, skel_bf, bpart);
    k_final         <<<1,     64, 0, stream>>>(bpart, out);
}

// Round 8
// 125.602 us; speedup vs baseline: 1.4178x; 1.0964x over previous
//
#include <hip/hip_runtime.h>
#include <math.h>

#define BATCH 32
#define MROWS 120
#define JDIM  64
#define DIM   512
#define NROW  (BATCH * MROWS)   // 3840

#define LOGIT_SCALE 14.285714285714283f

typedef float  f4     __attribute__((ext_vector_type(4)));
typedef float  f32x4  __attribute__((ext_vector_type(4)));
typedef short  bf16x8 __attribute__((ext_vector_type(8)));
typedef unsigned short u16x4 __attribute__((ext_vector_type(4)));

static __device__ __forceinline__ unsigned short f2bf(float f) {
    // round-to-nearest-even fp32 -> bf16 (inputs are finite normals)
    unsigned int u = __float_as_uint(f);
    u += 0x7FFFu + ((u >> 16) & 1u);
    return (unsigned short)(u >> 16);
}

// ---------------------------------------------------------------------------
// K1: skel_bf[b,m,:] = bf16( sum_j skeleton[b,m,j,:] / ||sum_j ...|| )
// one block per (b,m); 256 threads; linear nontemporal float4 stream.
// __launch_bounds__(256,4): cap VGPR <=128, guarantee >=4 blocks/CU.
// unroll 16: ~16KB in flight per wave.
// ---------------------------------------------------------------------------
__global__ __launch_bounds__(256, 4) void k_skel_mean_norm(
    const float* __restrict__ skel_in, unsigned short* __restrict__ skel_bf)
{
    const int row = blockIdx.x;          // b*120 + m
    const int t   = threadIdx.x;         // 0..255
    const int wid = t >> 6, lane = t & 63;

    const f4* __restrict__ src =
        (const f4*)(skel_in + (size_t)row * (JDIM * DIM));

    f4 acc0 = (f4){0.f, 0.f, 0.f, 0.f};
    f4 acc1 = (f4){0.f, 0.f, 0.f, 0.f};
    #pragma unroll 16
    for (int it = 0; it < 16; ++it) {
        f4 a = __builtin_nontemporal_load(&src[(2 * it + 0) * 256 + t]);
        f4 b = __builtin_nontemporal_load(&src[(2 * it + 1) * 256 + t]);
        acc0 += a;
        acc1 += b;
    }
    f4 acc = acc0 + acc1;

    // combine even-j half (t<128) with odd-j half (t+128), same d4 slot
    __shared__ f4 part[128];
    if (t >= 128) part[t - 128] = acc;
    __syncthreads();

    float ss = 0.f;
    if (t < 128) {
        acc += part[t];
        ss = acc.x * acc.x + acc.y * acc.y + acc.z * acc.z + acc.w * acc.w;
    }

    #pragma unroll
    for (int o = 32; o > 0; o >>= 1) ss += __shfl_xor(ss, o, 64);
    __shared__ float wsum[4];
    if (lane == 0) wsum[wid] = ss;
    __syncthreads();
    const float inv = 1.0f / sqrtf(wsum[0] + wsum[1] + wsum[2] + wsum[3]);

    if (t < 128) {
        u16x4 o;
        o.x = f2bf(acc.x * inv);
        o.y = f2bf(acc.y * inv);
        o.z = f2bf(acc.z * inv);
        o.w = f2bf(acc.w * inv);
        *(u16x4*)(skel_bf + (size_t)row * DIM + 4 * t) = o;
    }
}

// ---------------------------------------------------------------------------
// Kt: text_bf[b,m,:] = bf16( LOGIT_SCALE * text[b,m,:] / ||text[b,m,:]|| )
// one block per (b,m); 128 threads.
// ---------------------------------------------------------------------------
__global__ __launch_bounds__(128) void k_text_prep(
    const float* __restrict__ text, unsigned short* __restrict__ text_bf)
{
    const int row = blockIdx.x;          // b*120 + m
    const int t   = threadIdx.x;         // 0..127
    const int wid = t >> 6, lane = t & 63;

    f4 v = ((const f4*)(text + (size_t)row * DIM))[t];
    float ss = v.x * v.x + v.y * v.y + v.z * v.z + v.w * v.w;
    #pragma unroll
    for (int o = 32; o > 0; o >>= 1) ss += __shfl_xor(ss, o, 64);

    __shared__ float red[2];
    if (lane == 0) red[wid] = ss;
    __syncthreads();
    const float sc = LOGIT_SCALE / sqrtf(red[0] + red[1]);

    u16x4 o;
    o.x = f2bf(v.x * sc);
    o.y = f2bf(v.y * sc);
    o.z = f2bf(v.z * sc);
    o.w = f2bf(v.w * sc);
    *(u16x4*)(text_bf + (size_t)row * DIM + 4 * t) = o;
}

// ---------------------------------------------------------------------------
// K2: per batch b: logits(120x120) = text_bf(120x512) . skel_bf(120x512)^T
// via mfma_f32_16x16x32_bf16, then in-register row-LSE + diagonal.
// block = b (32 blocks, 512 threads = 8 waves). Wave w: rows 16w..16w+15,
// all 128 cols (8 col-tiles). C/D: col = lane&15, row = (lane>>4)*4 + reg.
// ---------------------------------------------------------------------------
__global__ __launch_bounds__(512) void k_logits_mfma(
    const unsigned short* __restrict__ text_bf,
    const unsigned short* __restrict__ skel_bf,
    float* __restrict__ bpart)
{
    const int b  = blockIdx.x;
    const int t  = threadIdx.x;
    const int w  = t >> 6;               // wave 0..7
    const int l  = t & 63;
    const int cl = l & 15;               // A-row / B-col within tile
    const int cg = l >> 4;               // k-subgroup; also C row-group

    const int arow = 16 * w + cl;
    const bool a_ok = (arow < MROWS);
    const unsigned short* __restrict__ ta =
        text_bf + ((size_t)b * MROWS + arow) * DIM;
    const unsigned short* __restrict__ sb =
        skel_bf + (size_t)b * MROWS * DIM;

    const bf16x8 zerov = (bf16x8){0,0,0,0,0,0,0,0};

    f32x4 acc[8];
    #pragma unroll
    for (int i = 0; i < 8; ++i) acc[i] = (f32x4){0.f, 0.f, 0.f, 0.f};

    for (int ks = 0; ks < 16; ++ks) {
        const int k0 = ks * 32 + cg * 8;
        const bf16x8 a = a_ok ? *(const bf16x8*)(ta + k0) : zerov;
        #pragma unroll
        for (int tc = 0; tc < 8; ++tc) {
            const int n = 16 * tc + cl;
            const bf16x8 bb = (n < MROWS)
                ? *(const bf16x8*)(sb + (size_t)n * DIM + k0) : zerov;
            acc[tc] = __builtin_amdgcn_mfma_f32_16x16x32_bf16(a, bb, acc[tc],
                                                              0, 0, 0);
        }
    }

    // per-row LSE + diagonal. Row (w, cg, r) = 16w + 4cg + r lives in the
    // 16 lanes of group cg, spread over 8 tiles (cols 16tc + cl).
    float csum = 0.f;
    #pragma unroll
    for (int r = 0; r < 4; ++r) {
        const int row = 16 * w + 4 * cg + r;

        float mx = -INFINITY;
        #pragma unroll
        for (int tc = 0; tc < 8; ++tc)
            if (16 * tc + cl < MROWS) mx = fmaxf(mx, acc[tc][r]);
        #pragma unroll
        for (int o = 1; o < 16; o <<= 1) mx = fmaxf(mx, __shfl_xor(mx, o, 16));

        float se = 0.f;
        #pragma unroll
        for (int tc = 0; tc < 8; ++tc)
            if (16 * tc + cl < MROWS) se += expf(acc[tc][r] - mx);
        #pragma unroll
        for (int o = 1; o < 16; o <<= 1) se += __shfl_xor(se, o, 16);

        // diagonal col == row -> tile tc = w, lane cl = 4cg + r
        if (row < MROWS && cl == 4 * cg + r)
            csum += acc[w][r] - (mx + logf(se));
    }

    #pragma unroll
    for (int o = 32; o > 0; o >>= 1) csum += __shfl_xor(csum, o, 64);
    __shared__ float wsums[8];
    if (l == 0) wsums[w] = csum;
    __syncthreads();
    if (t == 0) {
        float s = 0.f;
        #pragma unroll
        for (int i = 0; i < 8; ++i) s += wsums[i];
        bpart[b] = s;
    }
}

// ---------------------------------------------------------------------------
// K3: out = -sum(bpart) / NROW
// ---------------------------------------------------------------------------
__global__ __launch_bounds__(64) void k_final(
    const float* __restrict__ bpart, float* __restrict__ out)
{
    const int t = threadIdx.x;
    float s = (t < BATCH) ? bpart[t] : 0.f;
    #pragma unroll
    for (int o = 32; o > 0; o >>= 1) s += __shfl_xor(s, o, 64);
    if (t == 0) out[0] = -s * (1.0f / (float)NROW);
}

extern "C" void kernel_launch(void* const* d_in, const int* in_sizes, int n_in,
                              void* d_out, int out_size, void* d_ws, size_t ws_size,
                              hipStream_t stream)
{
    const float* skel_in = (const float*)d_in[0];   // (32,120,64,512) f32
    const float* text    = (const float*)d_in[1];   // (32,120,512)    f32
    float* out = (float*)d_out;

    unsigned short* skel_bf = (unsigned short*)d_ws;            // 3.93 MB
    unsigned short* text_bf = skel_bf + (size_t)NROW * DIM;     // 3.93 MB
    float*          bpart   = (float*)(text_bf + (size_t)NROW * DIM); // 32

    k_skel_mean_norm<<<NROW, 256, 0, stream>>>(skel_in, skel_bf);
    k_text_prep     <<<NROW, 128, 0, stream>>>(text, text_bf);
    k_logits_mfma   <<<BATCH, 512, 0, stream>>>(text_bf, skel_bf, bpart);
    k_final         <<<1,     64, 0, stream>>>(bpart, out);
}

// Round 9
// 106.805 us; speedup vs baseline: 1.6673x; 1.1760x over previous
//
#include <hip/hip_runtime.h>
#include <math.h>

#define BATCH 32
#define MROWS 120
#define JDIM  64
#define DIM   512
#define NROW  (BATCH * MROWS)   // 3840

#define LOGIT_SCALE 14.285714285714283f

typedef float  f4     __attribute__((ext_vector_type(4)));
typedef float  f32x4  __attribute__((ext_vector_type(4)));
typedef short  bf16x8 __attribute__((ext_vector_type(8)));
typedef unsigned short u16x4 __attribute__((ext_vector_type(4)));

static __device__ __forceinline__ unsigned short f2bf(float f) {
    // round-to-nearest-even fp32 -> bf16 (inputs are finite normals)
    unsigned int u = __float_as_uint(f);
    u += 0x7FFFu + ((u >> 16) & 1u);
    return (unsigned short)(u >> 16);
}

// ---------------------------------------------------------------------------
// K1 (FROZEN from R8): skel_bf[b,m,:] = bf16(normalize(sum_j skel[b,m,j,:]))
// one block per (b,m); 256 threads; linear nontemporal float4 stream.
// ---------------------------------------------------------------------------
__global__ __launch_bounds__(256, 4) void k_skel_mean_norm(
    const float* __restrict__ skel_in, unsigned short* __restrict__ skel_bf)
{
    const int row = blockIdx.x;          // b*120 + m
    const int t   = threadIdx.x;         // 0..255
    const int wid = t >> 6, lane = t & 63;

    const f4* __restrict__ src =
        (const f4*)(skel_in + (size_t)row * (JDIM * DIM));

    f4 acc0 = (f4){0.f, 0.f, 0.f, 0.f};
    f4 acc1 = (f4){0.f, 0.f, 0.f, 0.f};
    #pragma unroll 16
    for (int it = 0; it < 16; ++it) {
        f4 a = __builtin_nontemporal_load(&src[(2 * it + 0) * 256 + t]);
        f4 b = __builtin_nontemporal_load(&src[(2 * it + 1) * 256 + t]);
        acc0 += a;
        acc1 += b;
    }
    f4 acc = acc0 + acc1;

    __shared__ f4 part[128];
    if (t >= 128) part[t - 128] = acc;
    __syncthreads();

    float ss = 0.f;
    if (t < 128) {
        acc += part[t];
        ss = acc.x * acc.x + acc.y * acc.y + acc.z * acc.z + acc.w * acc.w;
    }

    #pragma unroll
    for (int o = 32; o > 0; o >>= 1) ss += __shfl_xor(ss, o, 64);
    __shared__ float wsum[4];
    if (lane == 0) wsum[wid] = ss;
    __syncthreads();
    const float inv = 1.0f / sqrtf(wsum[0] + wsum[1] + wsum[2] + wsum[3]);

    if (t < 128) {
        u16x4 o;
        o.x = f2bf(acc.x * inv);
        o.y = f2bf(acc.y * inv);
        o.z = f2bf(acc.z * inv);
        o.w = f2bf(acc.w * inv);
        *(u16x4*)(skel_bf + (size_t)row * DIM + 4 * t) = o;
    }
}

// ---------------------------------------------------------------------------
// Kt (FROZEN): text_bf[b,m,:] = bf16( LOGIT_SCALE * text / ||text|| )
// ---------------------------------------------------------------------------
__global__ __launch_bounds__(128) void k_text_prep(
    const float* __restrict__ text, unsigned short* __restrict__ text_bf)
{
    const int row = blockIdx.x;          // b*120 + m
    const int t   = threadIdx.x;         // 0..127
    const int wid = t >> 6, lane = t & 63;

    f4 v = ((const f4*)(text + (size_t)row * DIM))[t];
    float ss = v.x * v.x + v.y * v.y + v.z * v.z + v.w * v.w;
    #pragma unroll
    for (int o = 32; o > 0; o >>= 1) ss += __shfl_xor(ss, o, 64);

    __shared__ float red[2];
    if (lane == 0) red[wid] = ss;
    __syncthreads();
    const float sc = LOGIT_SCALE / sqrtf(red[0] + red[1]);

    u16x4 o;
    o.x = f2bf(v.x * sc);
    o.y = f2bf(v.y * sc);
    o.z = f2bf(v.z * sc);
    o.w = f2bf(v.w * sc);
    *(u16x4*)(text_bf + (size_t)row * DIM + 4 * t) = o;
}

// ---------------------------------------------------------------------------
// K2: 256 single-wave blocks (block = b*8 + w). Wave owns text rows
// 16w..16w+15 x all 128 cols: 8 col-tiles of mfma_f32_16x16x32_bf16,
// K-loop 16 steps. In-register row-LSE + diagonal (C/D: col=lane&15,
// row=(lane>>4)*4+reg). One partial sum per block -> bpart[256].
// Every wave on its own CU: 8x less per-CU L2 traffic than the 32-block
// version, no __syncthreads.
// ---------------------------------------------------------------------------
__global__ __launch_bounds__(64) void k_logits_mfma(
    const unsigned short* __restrict__ text_bf,
    const unsigned short* __restrict__ skel_bf,
    float* __restrict__ bpart)
{
    const int blk = blockIdx.x;          // b*8 + w
    const int b   = blk >> 3;
    const int w   = blk & 7;
    const int l   = threadIdx.x;         // 0..63
    const int cl  = l & 15;              // A-row / B-col within tile
    const int cg  = l >> 4;              // k-subgroup; C row-group

    const int arow = 16 * w + cl;
    const bool a_ok = (arow < MROWS);
    const unsigned short* __restrict__ ta =
        text_bf + ((size_t)b * MROWS + arow) * DIM;
    const unsigned short* __restrict__ sb =
        skel_bf + (size_t)b * MROWS * DIM;

    const bf16x8 zerov = (bf16x8){0,0,0,0,0,0,0,0};

    f32x4 acc[8];
    #pragma unroll
    for (int i = 0; i < 8; ++i) acc[i] = (f32x4){0.f, 0.f, 0.f, 0.f};

    for (int ks = 0; ks < 16; ++ks) {
        const int k0 = ks * 32 + cg * 8;
        const bf16x8 a = a_ok ? *(const bf16x8*)(ta + k0) : zerov;
        #pragma unroll
        for (int tc = 0; tc < 8; ++tc) {
            const int n = 16 * tc + cl;
            const bf16x8 bb = (n < MROWS)
                ? *(const bf16x8*)(sb + (size_t)n * DIM + k0) : zerov;
            acc[tc] = __builtin_amdgcn_mfma_f32_16x16x32_bf16(a, bb, acc[tc],
                                                              0, 0, 0);
        }
    }

    // per-row LSE + diagonal. Row (w,cg,r) = 16w+4cg+r lives in the 16
    // lanes of group cg (cols 16tc + cl).
    float csum = 0.f;
    #pragma unroll
    for (int r = 0; r < 4; ++r) {
        const int row = 16 * w + 4 * cg + r;

        float mx = -INFINITY;
        #pragma unroll
        for (int tc = 0; tc < 8; ++tc)
            if (16 * tc + cl < MROWS) mx = fmaxf(mx, acc[tc][r]);
        #pragma unroll
        for (int o = 1; o < 16; o <<= 1) mx = fmaxf(mx, __shfl_xor(mx, o, 16));

        float se = 0.f;
        #pragma unroll
        for (int tc = 0; tc < 8; ++tc)
            if (16 * tc + cl < MROWS) se += expf(acc[tc][r] - mx);
        #pragma unroll
        for (int o = 1; o < 16; o <<= 1) se += __shfl_xor(se, o, 16);

        // diagonal col == row -> tile tc = w, lane cl = 4cg + r
        if (row < MROWS && cl == 4 * cg + r)
            csum += acc[w][r] - (mx + logf(se));
    }

    #pragma unroll
    for (int o = 32; o > 0; o >>= 1) csum += __shfl_xor(csum, o, 64);
    if (l == 0) bpart[blk] = csum;
}

// ---------------------------------------------------------------------------
// K3: out = -sum(bpart[256]) / NROW
// ---------------------------------------------------------------------------
__global__ __launch_bounds__(64) void k_final(
    const float* __restrict__ bpart, float* __restrict__ out)
{
    const int t = threadIdx.x;
    float s = 0.f;
    #pragma unroll
    for (int k = 0; k < 4; ++k) s += bpart[t + 64 * k];
    #pragma unroll
    for (int o = 32; o > 0; o >>= 1) s += __shfl_xor(s, o, 64);
    if (t == 0) out[0] = -s * (1.0f / (float)NROW);
}

extern "C" void kernel_launch(void* const* d_in, const int* in_sizes, int n_in,
                              void* d_out, int out_size, void* d_ws, size_t ws_size,
                              hipStream_t stream)
{
    const float* skel_in = (const float*)d_in[0];   // (32,120,64,512) f32
    const float* text    = (const float*)d_in[1];   // (32,120,512)    f32
    float* out = (float*)d_out;

    unsigned short* skel_bf = (unsigned short*)d_ws;            // 3.93 MB
    unsigned short* text_bf = skel_bf + (size_t)NROW * DIM;     // 3.93 MB
    float*          bpart   = (float*)(text_bf + (size_t)NROW * DIM); // 256

    k_skel_mean_norm<<<NROW,      256, 0, stream>>>(skel_in, skel_bf);
    k_text_prep     <<<NROW,      128, 0, stream>>>(text, text_bf);
    k_logits_mfma   <<<BATCH * 8,  64, 0, stream>>>(text_bf, skel_bf, bpart);
    k_final         <<<1,          64, 0, stream>>>(bpart, out);
}

// Round 10
// 106.237 us; speedup vs baseline: 1.6762x; 1.0053x over previous
//
#include <hip/hip_runtime.h>
#include <math.h>

#define BATCH 32
#define MROWS 120
#define JDIM  64
#define DIM   512
#define NROW  (BATCH * MROWS)   // 3840

#define LOGIT_SCALE 14.285714285714283f

typedef float  f4     __attribute__((ext_vector_type(4)));
typedef float  f32x4  __attribute__((ext_vector_type(4)));
typedef short  bf16x8 __attribute__((ext_vector_type(8)));
typedef unsigned short u16x4 __attribute__((ext_vector_type(4)));

static __device__ __forceinline__ unsigned short f2bf(float f) {
    // round-to-nearest-even fp32 -> bf16 (inputs are finite normals)
    unsigned int u = __float_as_uint(f);
    u += 0x7FFFu + ((u >> 16) & 1u);
    return (unsigned short)(u >> 16);
}

// ---------------------------------------------------------------------------
// K1: skel_bf[b,m,:] = bf16(normalize(sum_j skel[b,m,j,:]))
// one block per (b,m); 256 threads. NEW: wave w reads a CONTIGUOUS 32 KB
// sub-slab sequentially (f4 index = w*2048 + it*64 + lane) -> each wave is
// one clean sequential DRAM stream (was: 4 KB-strided chunks).
// Bookkeeping: even it -> d4-slot `lane`, odd it -> `lane+64`;
// j = w*16 + it/2. Cross-wave combine via LDS.
// ---------------------------------------------------------------------------
__global__ __launch_bounds__(256, 4) void k_skel_mean_norm(
    const float* __restrict__ skel_in, unsigned short* __restrict__ skel_bf)
{
    const int row = blockIdx.x;          // b*120 + m
    const int t   = threadIdx.x;         // 0..255
    const int wid = t >> 6, lane = t & 63;

    const f4* __restrict__ base =
        (const f4*)(skel_in + (size_t)row * (JDIM * DIM)) + wid * 2048 + lane;

    f4 acc0 = (f4){0.f, 0.f, 0.f, 0.f};   // d4-slot = lane
    f4 acc1 = (f4){0.f, 0.f, 0.f, 0.f};   // d4-slot = lane + 64
    #pragma unroll 16
    for (int it2 = 0; it2 < 16; ++it2) {
        f4 a = __builtin_nontemporal_load(&base[it2 * 128]);        // even it
        f4 b = __builtin_nontemporal_load(&base[it2 * 128 + 64]);   // odd it
        acc0 += a;
        acc1 += b;
    }

    // cross-wave combine: lds[w][slot]
    __shared__ f4 lds[4][128];
    lds[wid][lane]      = acc0;
    lds[wid][lane + 64] = acc1;
    __syncthreads();

    f4 acc = (f4){0.f, 0.f, 0.f, 0.f};
    float ss = 0.f;
    if (t < 128) {
        acc = lds[0][t] + lds[1][t] + lds[2][t] + lds[3][t];
        ss = acc.x * acc.x + acc.y * acc.y + acc.z * acc.z + acc.w * acc.w;
    }

    #pragma unroll
    for (int o = 32; o > 0; o >>= 1) ss += __shfl_xor(ss, o, 64);
    __shared__ float wsum[2];
    if (t < 128 && lane == 0) wsum[wid] = ss;
    __syncthreads();
    const float inv = 1.0f / sqrtf(wsum[0] + wsum[1]);

    if (t < 128) {
        u16x4 o;
        o.x = f2bf(acc.x * inv);
        o.y = f2bf(acc.y * inv);
        o.z = f2bf(acc.z * inv);
        o.w = f2bf(acc.w * inv);
        *(u16x4*)(skel_bf + (size_t)row * DIM + 4 * t) = o;
    }
}

// ---------------------------------------------------------------------------
// Kt (FROZEN): text_bf[b,m,:] = bf16( LOGIT_SCALE * text / ||text|| )
// ---------------------------------------------------------------------------
__global__ __launch_bounds__(128) void k_text_prep(
    const float* __restrict__ text, unsigned short* __restrict__ text_bf)
{
    const int row = blockIdx.x;          // b*120 + m
    const int t   = threadIdx.x;         // 0..127
    const int wid = t >> 6, lane = t & 63;

    f4 v = ((const f4*)(text + (size_t)row * DIM))[t];
    float ss = v.x * v.x + v.y * v.y + v.z * v.z + v.w * v.w;
    #pragma unroll
    for (int o = 32; o > 0; o >>= 1) ss += __shfl_xor(ss, o, 64);

    __shared__ float red[2];
    if (lane == 0) red[wid] = ss;
    __syncthreads();
    const float sc = LOGIT_SCALE / sqrtf(red[0] + red[1]);

    u16x4 o;
    o.x = f2bf(v.x * sc);
    o.y = f2bf(v.y * sc);
    o.z = f2bf(v.z * sc);
    o.w = f2bf(v.w * sc);
    *(u16x4*)(text_bf + (size_t)row * DIM + 4 * t) = o;
}

// ---------------------------------------------------------------------------
// K2 (FROZEN): 256 single-wave blocks (block = b*8 + w). Wave owns text rows
// 16w..16w+15 x all 128 cols: 8 col-tiles of mfma_f32_16x16x32_bf16.
// In-register row-LSE + diagonal (C/D: col=lane&15, row=(lane>>4)*4+reg).
// ---------------------------------------------------------------------------
__global__ __launch_bounds__(64) void k_logits_mfma(
    const unsigned short* __restrict__ text_bf,
    const unsigned short* __restrict__ skel_bf,
    float* __restrict__ bpart)
{
    const int blk = blockIdx.x;          // b*8 + w
    const int b   = blk >> 3;
    const int w   = blk & 7;
    const int l   = threadIdx.x;         // 0..63
    const int cl  = l & 15;              // A-row / B-col within tile
    const int cg  = l >> 4;              // k-subgroup; C row-group

    const int arow = 16 * w + cl;
    const bool a_ok = (arow < MROWS);
    const unsigned short* __restrict__ ta =
        text_bf + ((size_t)b * MROWS + arow) * DIM;
    const unsigned short* __restrict__ sb =
        skel_bf + (size_t)b * MROWS * DIM;

    const bf16x8 zerov = (bf16x8){0,0,0,0,0,0,0,0};

    f32x4 acc[8];
    #pragma unroll
    for (int i = 0; i < 8; ++i) acc[i] = (f32x4){0.f, 0.f, 0.f, 0.f};

    for (int ks = 0; ks < 16; ++ks) {
        const int k0 = ks * 32 + cg * 8;
        const bf16x8 a = a_ok ? *(const bf16x8*)(ta + k0) : zerov;
        #pragma unroll
        for (int tc = 0; tc < 8; ++tc) {
            const int n = 16 * tc + cl;
            const bf16x8 bb = (n < MROWS)
                ? *(const bf16x8*)(sb + (size_t)n * DIM + k0) : zerov;
            acc[tc] = __builtin_amdgcn_mfma_f32_16x16x32_bf16(a, bb, acc[tc],
                                                              0, 0, 0);
        }
    }

    float csum = 0.f;
    #pragma unroll
    for (int r = 0; r < 4; ++r) {
        const int row = 16 * w + 4 * cg + r;

        float mx = -INFINITY;
        #pragma unroll
        for (int tc = 0; tc < 8; ++tc)
            if (16 * tc + cl < MROWS) mx = fmaxf(mx, acc[tc][r]);
        #pragma unroll
        for (int o = 1; o < 16; o <<= 1) mx = fmaxf(mx, __shfl_xor(mx, o, 16));

        float se = 0.f;
        #pragma unroll
        for (int tc = 0; tc < 8; ++tc)
            if (16 * tc + cl < MROWS) se += expf(acc[tc][r] - mx);
        #pragma unroll
        for (int o = 1; o < 16; o <<= 1) se += __shfl_xor(se, o, 16);

        if (row < MROWS && cl == 4 * cg + r)
            csum += acc[w][r] - (mx + logf(se));
    }

    #pragma unroll
    for (int o = 32; o > 0; o >>= 1) csum += __shfl_xor(csum, o, 64);
    if (l == 0) bpart[blk] = csum;
}

// ---------------------------------------------------------------------------
// K3 (FROZEN): out = -sum(bpart[256]) / NROW
// ---------------------------------------------------------------------------
__global__ __launch_bounds__(64) void k_final(
    const float* __restrict__ bpart, float* __restrict__ out)
{
    const int t = threadIdx.x;
    float s = 0.f;
    #pragma unroll
    for (int k = 0; k < 4; ++k) s += bpart[t + 64 * k];
    #pragma unroll
    for (int o = 32; o > 0; o >>= 1) s += __shfl_xor(s, o, 64);
    if (t == 0) out[0] = -s * (1.0f / (float)NROW);
}

extern "C" void kernel_launch(void* const* d_in, const int* in_sizes, int n_in,
                              void* d_out, int out_size, void* d_ws, size_t ws_size,
                              hipStream_t stream)
{
    const float* skel_in = (const float*)d_in[0];   // (32,120,64,512) f32
    const float* text    = (const float*)d_in[1];   // (32,120,512)    f32
    float* out = (float*)d_out;

    unsigned short* skel_bf = (unsigned short*)d_ws;            // 3.93 MB
    unsigned short* text_bf = skel_bf + (size_t)NROW * DIM;     // 3.93 MB
    float*          bpart   = (float*)(text_bf + (size_t)NROW * DIM); // 256

    k_skel_mean_norm<<<NROW,      256, 0, stream>>>(skel_in, skel_bf);
    k_text_prep     <<<NROW,      128, 0, stream>>>(text, text_bf);
    k_logits_mfma   <<<BATCH * 8,  64, 0, stream>>>(text_bf, skel_bf, bpart);
    k_final         <<<1,          64, 0, stream>>>(bpart, out);
}